// Round 4
// baseline (610.412 us; speedup 1.0000x reference)
//
#include <hip/hip_runtime.h>
#include <stdint.h>

#define B_   2
#define T_   2048
#define H_   2048
#define NH_  16
#define NKV_ 8
#define HD_  128

typedef unsigned short u16;
typedef __bf16 v8bf __attribute__((ext_vector_type(8)));
typedef short  v8s  __attribute__((ext_vector_type(8)));
typedef float  v4f  __attribute__((ext_vector_type(4)));

static __device__ __forceinline__ float b2f(u16 h) {
  union { unsigned u; float f; } x; x.u = ((unsigned)h) << 16; return x.f;
}
static __device__ __forceinline__ u16 f2b(float f) {
  union { float f; unsigned u; } x; x.f = f;
  unsigned r = x.u + 0x7fffu + ((x.u >> 16) & 1u);
  return (u16)(r >> 16);
}
static __device__ __forceinline__ v8bf asbf(v8s x) { return __builtin_bit_cast(v8bf, x); }

// ---------------------------------------------------------------------------
// Diagnostics
// ---------------------------------------------------------------------------
__global__ void zero_flags(unsigned* flags) {
  if (threadIdx.x < 16) flags[threadIdx.x] = 0;
}

__global__ __launch_bounds__(256) void nan_scan_f32(
    const float* __restrict__ buf, unsigned n, unsigned* __restrict__ flag)
{
  unsigned i = blockIdx.x * 256 + threadIdx.x;
  const unsigned stride = gridDim.x * 256;
  unsigned bad = 0;
  for (; i < n; i += stride) {
    const float v = buf[i];
    bad |= !(fabsf(v) <= 1e30f);     // NaN / Inf / absurd
  }
  if (bad) atomicOr(flag, 1u);
}

__global__ __launch_bounds__(256) void nan_scan_bf16(
    const u16* __restrict__ buf, unsigned n, unsigned* __restrict__ flag)
{
  unsigned i = blockIdx.x * 256 + threadIdx.x;
  const unsigned stride = gridDim.x * 256;
  unsigned bad = 0;
  for (; i < n; i += stride) {
    const unsigned v = buf[i] & 0x7FFFu;
    bad |= (v >= 0x7F80u);
  }
  if (bad) atomicOr(flag, 1u);
}

__global__ __launch_bounds__(256) void diag_fill_f32(
    float* __restrict__ out, unsigned n, const unsigned* __restrict__ flags)
{
  float marker = 0.f;
  #pragma unroll
  for (int s = 4; s >= 0; --s)
    if (flags[s]) marker = 777.f * (s + 1);
  if (marker == 0.f) return;
  unsigned i = blockIdx.x * 256 + threadIdx.x;
  const unsigned stride = gridDim.x * 256;
  for (; i < n; i += stride) out[i] = marker;
}

// ---------------------------------------------------------------------------
// f32 -> bf16 flat convert (vectorized float4 -> ushort4)
// ---------------------------------------------------------------------------
__global__ __launch_bounds__(256) void cvt_f32_bf16(
    const float* __restrict__ src, u16* __restrict__ dst, unsigned n4)
{
  unsigned i = blockIdx.x * 256 + threadIdx.x;
  const unsigned stride = gridDim.x * 256;
  for (; i < n4; i += stride) {
    const float4 v = ((const float4*)src)[i];
    ushort4 o;
    o.x = f2b(v.x); o.y = f2b(v.y); o.z = f2b(v.z); o.w = f2b(v.w);
    ((ushort4*)dst)[i] = o;
  }
}

// ---------------------------------------------------------------------------
// f32 src [R][C] -> bf16 dst [C][R], 64x64 LDS tiles.
// ---------------------------------------------------------------------------
__global__ __launch_bounds__(256) void transpose_f32_bf16(
    const float* __restrict__ src, u16* __restrict__ dst, int R, int C)
{
  __shared__ u16 tile[64][66];
  const int tc = blockIdx.x * 64, tr = blockIdx.y * 64;
  const int lc = threadIdx.x & 63, lr = threadIdx.x >> 6;
  #pragma unroll
  for (int rr = 0; rr < 64; rr += 4)
    tile[rr + lr][lc] = f2b(src[(size_t)(tr + rr + lr) * C + tc + lc]);
  __syncthreads();
  #pragma unroll
  for (int rr = 0; rr < 64; rr += 4)
    dst[(size_t)(tc + rr + lr) * R + tr + lc] = tile[lc][rr + lr];
}

// ---------------------------------------------------------------------------
// bf16 src [z][R][C] -> bf16 dst [z][C][R] (for V -> V^T)
// ---------------------------------------------------------------------------
__global__ __launch_bounds__(256) void transpose_bf16(
    const u16* __restrict__ src, u16* __restrict__ dst, int R, int C)
{
  __shared__ u16 tile[64][66];
  const int z = blockIdx.z;
  src += (size_t)z * R * C;
  dst += (size_t)z * R * C;
  const int tc = blockIdx.x * 64, tr = blockIdx.y * 64;
  const int lc = threadIdx.x & 63, lr = threadIdx.x >> 6;
  #pragma unroll
  for (int rr = 0; rr < 64; rr += 4)
    tile[rr + lr][lc] = src[(size_t)(tr + rr + lr) * C + tc + lc];
  __syncthreads();
  #pragma unroll
  for (int rr = 0; rr < 64; rr += 4)
    dst[(size_t)(tc + rr + lr) * R + tr + lc] = tile[lc][rr + lr];
}

// ---------------------------------------------------------------------------
// GEMM: C[M][N] = A[M][K] * Bt[N][K]^T, bf16 inputs, f32 accumulate.
// m97 structure: 128x128 tile, 4 waves, BK=32, global_load_lds width 16.
// F32OUT selects f32 vs bf16 output store.
// ---------------------------------------------------------------------------
template <bool F32OUT>
__global__ __launch_bounds__(256) void gemm_bt(
    const u16* __restrict__ A, const u16* __restrict__ Bt, void* __restrict__ Cout,
    int M, int N, int K)
{
  __shared__ __align__(16) u16 As[128 * 32];
  __shared__ __align__(16) u16 Bs[128 * 32];
  const int tid  = threadIdx.x;
  const int wave = tid >> 6, lane = tid & 63;
  const int l15  = lane & 15, quad = lane >> 4;
  const int wm   = (wave >> 1) * 64, wn = (wave & 1) * 64;
  const int m0   = blockIdx.y * 128, n0 = blockIdx.x * 128;

  {  // zero-init LDS: premature reads are finite
    const v8s pz = {0, 0, 0, 0, 0, 0, 0, 0};
    #pragma unroll
    for (int i = 0; i < 2; ++i) {
      ((v8s*)As)[tid + i * 256] = pz;
      ((v8s*)Bs)[tid + i * 256] = pz;
    }
  }

  const int srow = wave * 32 + (lane >> 2);
  const int scol = (lane & 3) * 8;

  v4f acc[4][4];
  const v4f z4 = {0.f, 0.f, 0.f, 0.f};
  #pragma unroll
  for (int i = 0; i < 4; ++i)
    #pragma unroll
    for (int j = 0; j < 4; ++j) acc[i][j] = z4;

  for (int k0 = 0; k0 < K; k0 += 32) {
    __syncthreads();
    #pragma unroll
    for (int l = 0; l < 2; ++l) {
      const u16* ga = A + (size_t)(m0 + srow + l * 16) * K + k0 + scol;
      __builtin_amdgcn_global_load_lds(
          (const __attribute__((address_space(1))) void*)ga,
          (__attribute__((address_space(3))) void*)((char*)As + (wave * 2 + l) * 1024),
          16, 0, 0);
      const u16* gb = Bt + (size_t)(n0 + srow + l * 16) * K + k0 + scol;
      __builtin_amdgcn_global_load_lds(
          (const __attribute__((address_space(1))) void*)gb,
          (__attribute__((address_space(3))) void*)((char*)Bs + (wave * 2 + l) * 1024),
          16, 0, 0);
    }
    __builtin_amdgcn_s_waitcnt(0);
    __syncthreads();
    v8s a[4], b[4];
    #pragma unroll
    for (int mi = 0; mi < 4; ++mi)
      a[mi] = *(const v8s*)&As[(wm + mi * 16 + l15) * 32 + quad * 8];
    #pragma unroll
    for (int ni = 0; ni < 4; ++ni)
      b[ni] = *(const v8s*)&Bs[(wn + ni * 16 + l15) * 32 + quad * 8];
    #pragma unroll
    for (int mi = 0; mi < 4; ++mi)
      #pragma unroll
      for (int ni = 0; ni < 4; ++ni)
        acc[mi][ni] = __builtin_amdgcn_mfma_f32_16x16x32_bf16(
            asbf(a[mi]), asbf(b[ni]), acc[mi][ni], 0, 0, 0);
  }
  #pragma unroll
  for (int mi = 0; mi < 4; ++mi)
    #pragma unroll
    for (int ni = 0; ni < 4; ++ni)
      #pragma unroll
      for (int r = 0; r < 4; ++r) {
        const int m = m0 + wm + mi * 16 + quad * 4 + r;
        const int n = n0 + wn + ni * 16 + l15;
        if (F32OUT) ((float*)Cout)[(size_t)m * N + n] = acc[mi][ni][r];
        else        ((u16*)Cout)[(size_t)m * N + n]  = f2b(acc[mi][ni][r]);
      }
}

// ---------------------------------------------------------------------------
// Per-head RMSNorm + RoPE + scatter (QKV bf16 in, qw/kw f32).
// ---------------------------------------------------------------------------
__global__ __launch_bounds__(256) void norm_rope_scatter(
    const u16* __restrict__ QKV, const float* __restrict__ qw, const float* __restrict__ kw,
    u16* __restrict__ Qh, u16* __restrict__ Kh, u16* __restrict__ Vh)
{
  const int vid  = blockIdx.x * 4 + (threadIdx.x >> 6);
  const int lane = threadIdx.x & 63;
  const int head = vid & 31;
  const int bt   = vid >> 5;
  const int b    = bt >> 11, t = bt & (T_ - 1);
  const int colbase = head < 16 ? head * 128
                    : (head < 24 ? 2048 + (head - 16) * 128
                                 : 3072 + (head - 24) * 128);
  const u16* src = QKV + (size_t)bt * 4096 + colbase;
  const u16 r1 = src[lane], r2 = src[lane + 64];
  if (head >= 24) {  // V: pure scatter
    u16* dst = Vh + ((size_t)(b * NKV_ + (head - 24)) * T_ + t) * 128;
    dst[lane] = r1; dst[lane + 64] = r2;
    return;
  }
  float x1 = b2f(r1), x2 = b2f(r2);
  float ss = x1 * x1 + x2 * x2;
  #pragma unroll
  for (int d = 1; d < 64; d <<= 1) ss += __shfl_xor(ss, d, 64);
  const float rinv = rsqrtf(ss * (1.f / 128.f) + 1e-6f);
  const float* w = head < 16 ? qw : kw;
  const float n1 = x1 * rinv * w[lane];
  const float n2 = x2 * rinv * w[lane + 64];
  const float invf = exp2f(-(float)lane * (19.931568569324174f / 64.f));
  const float ang  = (float)t * invf;
  const float c = cosf(ang), s = sinf(ang);
  const float o1 = n1 * c - n2 * s;
  const float o2 = n2 * c + n1 * s;
  u16* dst = (head < 16)
      ? Qh + ((size_t)(b * NH_ + head) * T_ + t) * 128
      : Kh + ((size_t)(b * NKV_ + (head - 16)) * T_ + t) * 128;
  dst[lane]      = f2b(o1);
  dst[lane + 64] = f2b(o2);
}

// ---------------------------------------------------------------------------
// Flash attention (structure unchanged).
// ---------------------------------------------------------------------------
__global__ __launch_bounds__(256) void attn_fused(
    const u16* __restrict__ Qh, const u16* __restrict__ Kh,
    const u16* __restrict__ VhT, u16* __restrict__ ctx)
{
  __shared__ __align__(16) u16 Plds[4][32 * 32];
  {
    const v8s pz = {0, 0, 0, 0, 0, 0, 0, 0};
    #pragma unroll
    for (int i = 0; i < 2; ++i)
      ((v8s*)Plds)[threadIdx.x + i * 256] = pz;
    __syncthreads();
  }
  const int wave = threadIdx.x >> 6, lane = threadIdx.x & 63;
  const int l15 = lane & 15, quad = lane >> 4;
  const int bid = blockIdx.x;
  const int pg = bid & 7, h = (bid >> 3) & 15, b = bid >> 7;
  const int pair = pg * 4 + wave;
  const u16* Qb = Qh  + (size_t)(b * NH_ + h) * T_ * 128;
  const u16* Kb = Kh  + (size_t)(b * NKV_ + (h >> 1)) * T_ * 128;
  const u16* Vb = VhT + (size_t)(b * NKV_ + (h >> 1)) * 128 * T_;
  u16* Pl = Plds[wave];
  const float scale = 0.08838834764831845f;
  const v4f z4 = {0.f, 0.f, 0.f, 0.f};

  for (int rep = 0; rep < 2; ++rep) {
    const int qt = (rep == 0) ? pair : 63 - pair;
    const int q0 = qt * 32;

    v8s qf[2][4];
    #pragma unroll
    for (int mi = 0; mi < 2; ++mi)
      #pragma unroll
      for (int c = 0; c < 4; ++c)
        qf[mi][c] = *(const v8s*)(Qb + (size_t)(q0 + mi * 16 + l15) * 128 + c * 32 + quad * 8);

    v4f o[2][8];
    #pragma unroll
    for (int mi = 0; mi < 2; ++mi)
      #pragma unroll
      for (int di = 0; di < 8; ++di) o[mi][di] = z4;
    float mrow[2][4], lrow[2][4];
    #pragma unroll
    for (int mi = 0; mi < 2; ++mi)
      #pragma unroll
      for (int r = 0; r < 4; ++r) { mrow[mi][r] = -1e30f; lrow[mi][r] = 0.f; }

    for (int j0 = 0; j0 <= q0; j0 += 32) {
      v4f s[2][2];
      s[0][0] = z4; s[0][1] = z4; s[1][0] = z4; s[1][1] = z4;
      #pragma unroll
      for (int ni = 0; ni < 2; ++ni)
        #pragma unroll
        for (int c = 0; c < 4; ++c) {
          const v8s kf = *(const v8s*)(Kb + (size_t)(j0 + ni * 16 + l15) * 128 + c * 32 + quad * 8);
          s[0][ni] = __builtin_amdgcn_mfma_f32_16x16x32_bf16(asbf(qf[0][c]), asbf(kf), s[0][ni], 0, 0, 0);
          s[1][ni] = __builtin_amdgcn_mfma_f32_16x16x32_bf16(asbf(qf[1][c]), asbf(kf), s[1][ni], 0, 0, 0);
        }
      const bool diag = (j0 == q0);
      float alpha[2][4];
      #pragma unroll
      for (int mi = 0; mi < 2; ++mi)
        #pragma unroll
        for (int r = 0; r < 4; ++r) {
          const int qrow = mi * 16 + quad * 4 + r;
          float v0 = s[mi][0][r] * scale;
          float v1 = s[mi][1][r] * scale;
          if (diag) {
            if (l15 > qrow)      v0 = -1e30f;
            if (16 + l15 > qrow) v1 = -1e30f;
          }
          float mx = fmaxf(v0, v1);
          #pragma unroll
          for (int d = 1; d < 16; d <<= 1) mx = fmaxf(mx, __shfl_xor(mx, d, 64));
          const float mnew = fmaxf(mrow[mi][r], mx);
          const float al = __expf(mrow[mi][r] - mnew);
          const float p0 = __expf(v0 - mnew);
          const float p1 = __expf(v1 - mnew);
          float ps = p0 + p1;
          #pragma unroll
          for (int d = 1; d < 16; d <<= 1) ps += __shfl_xor(ps, d, 64);
          mrow[mi][r] = mnew;
          lrow[mi][r] = lrow[mi][r] * al + ps;
          alpha[mi][r] = al;
          Pl[qrow * 32 + l15]      = f2b(p0);
          Pl[qrow * 32 + 16 + l15] = f2b(p1);
        }
      #pragma unroll
      for (int mi = 0; mi < 2; ++mi)
        #pragma unroll
        for (int di = 0; di < 8; ++di) {
          v4f t_ = o[mi][di];
          t_[0] *= alpha[mi][0]; t_[1] *= alpha[mi][1];
          t_[2] *= alpha[mi][2]; t_[3] *= alpha[mi][3];
          o[mi][di] = t_;
        }
      __builtin_amdgcn_s_waitcnt(0);
      v8s pf[2];
      pf[0] = *(const v8s*)&Pl[l15 * 32 + quad * 8];
      pf[1] = *(const v8s*)&Pl[(16 + l15) * 32 + quad * 8];
      #pragma unroll
      for (int di = 0; di < 8; ++di) {
        const v8s vt = *(const v8s*)(Vb + (size_t)(di * 16 + l15) * T_ + j0 + quad * 8);
        o[0][di] = __builtin_amdgcn_mfma_f32_16x16x32_bf16(asbf(pf[0]), asbf(vt), o[0][di], 0, 0, 0);
        o[1][di] = __builtin_amdgcn_mfma_f32_16x16x32_bf16(asbf(pf[1]), asbf(vt), o[1][di], 0, 0, 0);
      }
    }
    #pragma unroll
    for (int mi = 0; mi < 2; ++mi) {
      float inv[4];
      #pragma unroll
      for (int r = 0; r < 4; ++r) inv[r] = 1.f / lrow[mi][r];
      #pragma unroll
      for (int di = 0; di < 8; ++di)
        #pragma unroll
        for (int r = 0; r < 4; ++r) {
          const int t   = q0 + mi * 16 + quad * 4 + r;
          const int col = h * 128 + di * 16 + l15;
          ctx[(size_t)(b * T_ + t) * (NH_ * HD_) + col] = f2b(o[mi][di][r] * inv[r]);
        }
    }
  }
}

// ---------------------------------------------------------------------------
extern "C" void kernel_launch(void* const* d_in, const int* in_sizes, int n_in,
                              void* d_out, int out_size, void* d_ws, size_t ws_size,
                              hipStream_t stream) {
  (void)in_sizes; (void)n_in; (void)out_size; (void)ws_size;
  const float* x  = (const float*)d_in[0];
  // d_in[1] = attn_mask (causal; applied analytically)
  const float* Wq = (const float*)d_in[2];
  const float* Wk = (const float*)d_in[3];
  const float* Wv = (const float*)d_in[4];
  const float* Wo = (const float*)d_in[5];
  const float* qw = (const float*)d_in[6];
  const float* kw = (const float*)d_in[7];
  float* out = (float*)d_out;

  // workspace (bf16 internals, lifetime-aliased; total 67.1 MB):
  char* ws = (char*)d_ws;
  u16* WoT   = (u16*)(ws);                    // [2048][2048]       8.39 MB (live to end)
  u16* x_bf  = (u16*)(ws + 8388608);          // [4096][2048]      16.78 MB (dead after QKV gemm)
  u16* Vh    = (u16*)(ws + 8388608);          //  aliases x_bf[0:8.39MB]
  u16* VhT   = (u16*)(ws + 16777216);         //  aliases x_bf[8.39:16.78MB]
  u16* WqkvT = (u16*)(ws + 25165824);         // [4096][2048]      16.78 MB (dead after QKV gemm)
  u16* ctx   = (u16*)(ws + 25165824);         //  aliases WqkvT
  u16* Qh    = (u16*)(ws + 41943040);         // [2][16][2048][128] 16.78 MB
  u16* Kh    = (u16*)(ws + 58720256);         // [2][8][2048][128]   8.39 MB
  unsigned* flags = (unsigned*)(ws + 67108864);
  // QKV bf16 [4096][4096] scratch = 33.55 MB lives in d_out (f32 8.4M elems),
  // dead before the final f32 GEMM overwrites d_out.
  u16* QKV = (u16*)d_out;

  zero_flags<<<1, 64, 0, stream>>>(flags);
  // stage 0: inputs finite as f32?
  nan_scan_f32<<<1024, 256, 0, stream>>>(x,  8388608u, flags + 0);
  nan_scan_f32<<<1024, 256, 0, stream>>>(Wq, 4194304u, flags + 0);
  nan_scan_f32<<<1024, 256, 0, stream>>>(Wk, 2097152u, flags + 0);
  nan_scan_f32<<<1024, 256, 0, stream>>>(Wv, 2097152u, flags + 0);
  nan_scan_f32<<<1024, 256, 0, stream>>>(Wo, 4194304u, flags + 0);

  // convert / transpose weights and activations to bf16
  cvt_f32_bf16<<<2048, 256, 0, stream>>>(x, x_bf, 2097152u);
  transpose_f32_bf16<<<dim3(32, 32), 256, 0, stream>>>(Wq, WqkvT,               2048, 2048);
  transpose_f32_bf16<<<dim3(16, 32), 256, 0, stream>>>(Wk, WqkvT + 2048 * 2048, 2048, 1024);
  transpose_f32_bf16<<<dim3(16, 32), 256, 0, stream>>>(Wv, WqkvT + 3072 * 2048, 2048, 1024);
  transpose_f32_bf16<<<dim3(32, 32), 256, 0, stream>>>(Wo, WoT,                 2048, 2048);

  // QKV projection (bf16 out into d_out scratch)
  gemm_bt<false><<<dim3(32, 32), 256, 0, stream>>>(x_bf, WqkvT, QKV, 4096, 4096, 2048);
  nan_scan_bf16<<<1024, 256, 0, stream>>>(QKV, 16777216u, flags + 1);   // stage 1

  norm_rope_scatter<<<dim3(32768), 256, 0, stream>>>(QKV, qw, kw, Qh, Kh, Vh);
  transpose_bf16<<<dim3(2, 32, 16), 256, 0, stream>>>(Vh, VhT, 2048, 128);
  nan_scan_bf16<<<1024, 256, 0, stream>>>(Qh,  8388608u, flags + 2);    // stage 2
  nan_scan_bf16<<<1024, 256, 0, stream>>>(Kh,  4194304u, flags + 2);
  nan_scan_bf16<<<1024, 256, 0, stream>>>(VhT, 4194304u, flags + 2);

  attn_fused<<<dim3(256), 256, 0, stream>>>(Qh, Kh, VhT, ctx);
  nan_scan_bf16<<<1024, 256, 0, stream>>>(ctx, 8388608u, flags + 3);    // stage 3

  // output projection: f32 store into d_out (overwrites QKV scratch fully)
  gemm_bt<true><<<dim3(16, 32), 256, 0, stream>>>(ctx, WoT, (void*)out, 4096, 2048, 2048);
  nan_scan_f32<<<1024, 256, 0, stream>>>(out, 8388608u, flags + 4);     // stage 4

  diag_fill_f32<<<1024, 256, 0, stream>>>(out, 8388608u, flags);
}

// Round 5
// 467.429 us; speedup vs baseline: 1.3059x; 1.3059x over previous
//
#include <hip/hip_runtime.h>
#include <stdint.h>

#define B_   2
#define T_   2048
#define H_   2048
#define NH_  16
#define NKV_ 8
#define HD_  128

typedef unsigned short u16;
typedef __bf16 v8bf __attribute__((ext_vector_type(8)));
typedef short  v8s  __attribute__((ext_vector_type(8)));
typedef float  v4f  __attribute__((ext_vector_type(4)));

static __device__ __forceinline__ float b2f(u16 h) {
  union { unsigned u; float f; } x; x.u = ((unsigned)h) << 16; return x.f;
}
static __device__ __forceinline__ u16 f2b(float f) {
  union { float f; unsigned u; } x; x.f = f;
  unsigned r = x.u + 0x7fffu + ((x.u >> 16) & 1u);
  return (u16)(r >> 16);
}
static __device__ __forceinline__ v8bf asbf(v8s x) { return __builtin_bit_cast(v8bf, x); }

// ---------------------------------------------------------------------------
// f32 -> bf16 flat convert (float4 -> ushort4)
// ---------------------------------------------------------------------------
__global__ __launch_bounds__(256) void cvt_f32_bf16(
    const float* __restrict__ src, u16* __restrict__ dst, unsigned n4)
{
  unsigned i = blockIdx.x * 256 + threadIdx.x;
  const unsigned stride = gridDim.x * 256;
  for (; i < n4; i += stride) {
    const float4 v = ((const float4*)src)[i];
    ushort4 o;
    o.x = f2b(v.x); o.y = f2b(v.y); o.z = f2b(v.z); o.w = f2b(v.w);
    ((ushort4*)dst)[i] = o;
  }
}

// ---------------------------------------------------------------------------
// f32 src [R][C] -> bf16 dst [C][R], 64x64 LDS tiles.
// ---------------------------------------------------------------------------
__global__ __launch_bounds__(256) void transpose_f32_bf16(
    const float* __restrict__ src, u16* __restrict__ dst, int R, int C)
{
  __shared__ u16 tile[64][66];
  const int tc = blockIdx.x * 64, tr = blockIdx.y * 64;
  const int lc = threadIdx.x & 63, lr = threadIdx.x >> 6;
  #pragma unroll
  for (int rr = 0; rr < 64; rr += 4)
    tile[rr + lr][lc] = f2b(src[(size_t)(tr + rr + lr) * C + tc + lc]);
  __syncthreads();
  #pragma unroll
  for (int rr = 0; rr < 64; rr += 4)
    dst[(size_t)(tc + rr + lr) * R + tr + lc] = tile[lc][rr + lr];
}

// ---------------------------------------------------------------------------
// bf16 src [z][R][C] -> bf16 dst [z][C][R], separate z-strides (V -> V^T into
// the 144-row padded VhT).
// ---------------------------------------------------------------------------
__global__ __launch_bounds__(256) void transpose_bf16(
    const u16* __restrict__ src, u16* __restrict__ dst, int R, int C,
    long srcZ, long dstZ)
{
  __shared__ u16 tile[64][66];
  const int z = blockIdx.z;
  src += (size_t)z * srcZ;
  dst += (size_t)z * dstZ;
  const int tc = blockIdx.x * 64, tr = blockIdx.y * 64;
  const int lc = threadIdx.x & 63, lr = threadIdx.x >> 6;
  #pragma unroll
  for (int rr = 0; rr < 64; rr += 4)
    tile[rr + lr][lc] = src[(size_t)(tr + rr + lr) * C + tc + lc];
  __syncthreads();
  #pragma unroll
  for (int rr = 0; rr < 64; rr += 4)
    dst[(size_t)(tc + rr + lr) * R + tr + lc] = tile[lc][rr + lr];
}

// ---------------------------------------------------------------------------
// VhTp [16][144][2048]: fill row 128 with bf16 1.0 (the "ones" denominator
// row), rows 129..143 with 0.
// ---------------------------------------------------------------------------
__global__ __launch_bounds__(256) void fill_vones(u16* __restrict__ VhTp)
{
  const int z = blockIdx.x >> 4, ri = blockIdx.x & 15;
  const u16 val = (ri == 0) ? (u16)0x3F80 : (u16)0;
  u16* row = VhTp + ((size_t)z * 144 + 128 + ri) * T_;
  for (int i = threadIdx.x; i < T_; i += 256) row[i] = val;
}

// ---------------------------------------------------------------------------
// GEMM: C[M][N] = A[M][K] * Bt[N][K]^T, bf16 inputs, f32 accumulate.
// m97 structure: 128x128 tile, 4 waves, BK=32, global_load_lds width 16.
// ---------------------------------------------------------------------------
template <bool F32OUT>
__global__ __launch_bounds__(256) void gemm_bt(
    const u16* __restrict__ A, const u16* __restrict__ Bt, void* __restrict__ Cout,
    int M, int N, int K)
{
  __shared__ __align__(16) u16 As[128 * 32];
  __shared__ __align__(16) u16 Bs[128 * 32];
  const int tid  = threadIdx.x;
  const int wave = tid >> 6, lane = tid & 63;
  const int l15  = lane & 15, quad = lane >> 4;
  const int wm   = (wave >> 1) * 64, wn = (wave & 1) * 64;
  const int m0   = blockIdx.y * 128, n0 = blockIdx.x * 128;

  const int srow = wave * 32 + (lane >> 2);
  const int scol = (lane & 3) * 8;

  v4f acc[4][4];
  const v4f z4 = {0.f, 0.f, 0.f, 0.f};
  #pragma unroll
  for (int i = 0; i < 4; ++i)
    #pragma unroll
    for (int j = 0; j < 4; ++j) acc[i][j] = z4;

  for (int k0 = 0; k0 < K; k0 += 32) {
    __syncthreads();
    #pragma unroll
    for (int l = 0; l < 2; ++l) {
      const u16* ga = A + (size_t)(m0 + srow + l * 16) * K + k0 + scol;
      __builtin_amdgcn_global_load_lds(
          (const __attribute__((address_space(1))) void*)ga,
          (__attribute__((address_space(3))) void*)((char*)As + (wave * 2 + l) * 1024),
          16, 0, 0);
      const u16* gb = Bt + (size_t)(n0 + srow + l * 16) * K + k0 + scol;
      __builtin_amdgcn_global_load_lds(
          (const __attribute__((address_space(1))) void*)gb,
          (__attribute__((address_space(3))) void*)((char*)Bs + (wave * 2 + l) * 1024),
          16, 0, 0);
    }
    __builtin_amdgcn_s_waitcnt(0);
    __syncthreads();
    v8s a[4], b[4];
    #pragma unroll
    for (int mi = 0; mi < 4; ++mi)
      a[mi] = *(const v8s*)&As[(wm + mi * 16 + l15) * 32 + quad * 8];
    #pragma unroll
    for (int ni = 0; ni < 4; ++ni)
      b[ni] = *(const v8s*)&Bs[(wn + ni * 16 + l15) * 32 + quad * 8];
    #pragma unroll
    for (int mi = 0; mi < 4; ++mi)
      #pragma unroll
      for (int ni = 0; ni < 4; ++ni)
        acc[mi][ni] = __builtin_amdgcn_mfma_f32_16x16x32_bf16(
            asbf(a[mi]), asbf(b[ni]), acc[mi][ni], 0, 0, 0);
  }
  #pragma unroll
  for (int mi = 0; mi < 4; ++mi)
    #pragma unroll
    for (int ni = 0; ni < 4; ++ni)
      #pragma unroll
      for (int r = 0; r < 4; ++r) {
        const int m = m0 + wm + mi * 16 + quad * 4 + r;
        const int n = n0 + wn + ni * 16 + l15;
        if (F32OUT) ((float*)Cout)[(size_t)m * N + n] = acc[mi][ni][r];
        else        ((u16*)Cout)[(size_t)m * N + n]  = f2b(acc[mi][ni][r]);
      }
}

// ---------------------------------------------------------------------------
// Per-head RMSNorm + RoPE + scatter (QKV bf16 in, qw/kw f32).
// ---------------------------------------------------------------------------
__global__ __launch_bounds__(256) void norm_rope_scatter(
    const u16* __restrict__ QKV, const float* __restrict__ qw, const float* __restrict__ kw,
    u16* __restrict__ Qh, u16* __restrict__ Kh, u16* __restrict__ Vh)
{
  const int vid  = blockIdx.x * 4 + (threadIdx.x >> 6);
  const int lane = threadIdx.x & 63;
  const int head = vid & 31;
  const int bt   = vid >> 5;
  const int b    = bt >> 11, t = bt & (T_ - 1);
  const int colbase = head < 16 ? head * 128
                    : (head < 24 ? 2048 + (head - 16) * 128
                                 : 3072 + (head - 24) * 128);
  const u16* src = QKV + (size_t)bt * 4096 + colbase;
  const u16 r1 = src[lane], r2 = src[lane + 64];
  if (head >= 24) {  // V: pure scatter
    u16* dst = Vh + ((size_t)(b * NKV_ + (head - 24)) * T_ + t) * 128;
    dst[lane] = r1; dst[lane + 64] = r2;
    return;
  }
  float x1 = b2f(r1), x2 = b2f(r2);
  float ss = x1 * x1 + x2 * x2;
  #pragma unroll
  for (int d = 1; d < 64; d <<= 1) ss += __shfl_xor(ss, d, 64);
  const float rinv = rsqrtf(ss * (1.f / 128.f) + 1e-6f);
  const float* w = head < 16 ? qw : kw;
  const float n1 = x1 * rinv * w[lane];
  const float n2 = x2 * rinv * w[lane + 64];
  const float invf = exp2f(-(float)lane * (19.931568569324174f / 64.f));
  const float ang  = (float)t * invf;
  const float c = cosf(ang), s = sinf(ang);
  const float o1 = n1 * c - n2 * s;
  const float o2 = n2 * c + n1 * s;
  u16* dst = (head < 16)
      ? Qh + ((size_t)(b * NH_ + head) * T_ + t) * 128
      : Kh + ((size_t)(b * NKV_ + (head - 16)) * T_ + t) * 128;
  dst[lane]      = f2b(o1);
  dst[lane + 64] = f2b(o2);
}

// ---------------------------------------------------------------------------
// Flash attention v2 — fixed-max softmax (shift-invariance: RMSNorm bounds
// |s|*scale <= sqrt(128)=11.31, so a constant max is numerically safe; f32
// accumulators absorb 2^+-33). Denominator l comes from a "ones" row appended
// to V^T (row 128 of the 144-row padded VhTp) -> one extra MFMA column, zero
// cross-lane reductions in the inner loop.
// Parallelism: each 32-row q-tile is split into two key-halves handled by
// sibling waves; partial (O,l) merge by simple addition via an LDS combine.
// 1024 blocks x 4 waves = 4096 waves (2 waves/SIMD). Balanced: block handles
// pair (g, 63-g) -> 65 tile-iters per block, max wave 33.
// ---------------------------------------------------------------------------
__global__ __launch_bounds__(256) void attn_fused2(
    const u16* __restrict__ Qh, const u16* __restrict__ Kh,
    const u16* __restrict__ VhTp, u16* __restrict__ ctx)
{
  // P tile: stride 40 shorts (80 B: rows 16B-aligned for ds_read_b128,
  // quad-row phase 16 banks apart -> ~4-way write conflicts vs 8-way at 32)
  __shared__ __align__(16) u16 Plds[4][32 * 40];
  __shared__ v4f Olds[2][18][64];     // [pair][mi*9+di][lane] partial f32 acc

  const int wave = threadIdx.x >> 6, lane = threadIdx.x & 63;
  const int l15 = lane & 15, quad = lane >> 4;
  const int bid = blockIdx.x;
  const int g = bid & 31, h = (bid >> 5) & 15, b = bid >> 9;
  const int pairsel = wave >> 1;        // which q-tile of the pair
  const int half    = wave & 1;         // which key-half
  const int qt = pairsel ? (63 - g) : g;
  const int q0 = qt * 32;
  const int nt = qt + 1;                // key tiles for this q-tile
  const int jt0 = half ? (nt >> 1) : 0;
  const int jt1 = half ? nt : (nt >> 1);

  const u16* Qb = Qh   + (size_t)(b * NH_ + h) * T_ * 128;
  const u16* Kb = Kh   + (size_t)(b * NKV_ + (h >> 1)) * T_ * 128;
  const u16* Vb = VhTp + (size_t)(b * NKV_ + (h >> 1)) * 144 * T_;
  u16* Pl = Plds[wave];

  // p = 2^(s*k2 - C2), k2 = log2(e)/sqrt(128), C2 > max|s*k2| = 16.33
  const float k2 = 0.12751740f;
  const float C2 = 17.0f;
  const v4f z4 = {0.f, 0.f, 0.f, 0.f};

  v8s qf[2][4];
  #pragma unroll
  for (int mi = 0; mi < 2; ++mi)
    #pragma unroll
    for (int c = 0; c < 4; ++c)
      qf[mi][c] = *(const v8s*)(Qb + (size_t)(q0 + mi * 16 + l15) * 128 + c * 32 + quad * 8);

  v4f o[2][9];
  #pragma unroll
  for (int mi = 0; mi < 2; ++mi)
    #pragma unroll
    for (int di = 0; di < 9; ++di) o[mi][di] = z4;

  for (int jt = jt0; jt < jt1; ++jt) {
    const int j0 = jt * 32;
    // S = Q K^T for this 32x32 tile (16 MFMA)
    v4f s[2][2];
    s[0][0] = z4; s[0][1] = z4; s[1][0] = z4; s[1][1] = z4;
    #pragma unroll
    for (int ni = 0; ni < 2; ++ni)
      #pragma unroll
      for (int c = 0; c < 4; ++c) {
        const v8s kf = *(const v8s*)(Kb + (size_t)(j0 + ni * 16 + l15) * 128 + c * 32 + quad * 8);
        s[0][ni] = __builtin_amdgcn_mfma_f32_16x16x32_bf16(asbf(qf[0][c]), asbf(kf), s[0][ni], 0, 0, 0);
        s[1][ni] = __builtin_amdgcn_mfma_f32_16x16x32_bf16(asbf(qf[1][c]), asbf(kf), s[1][ni], 0, 0, 0);
      }
    const bool diag = (j0 == q0);
    // P = 2^(s*k2 - C2), causal-masked on the diagonal tile; straight to LDS
    #pragma unroll
    for (int mi = 0; mi < 2; ++mi)
      #pragma unroll
      for (int r = 0; r < 4; ++r) {
        const int qrow = mi * 16 + quad * 4 + r;
        float u0 = fmaf(s[mi][0][r], k2, -C2);
        float u1 = fmaf(s[mi][1][r], k2, -C2);
        if (diag) {
          if (l15 > qrow)      u0 = -1e30f;
          if (16 + l15 > qrow) u1 = -1e30f;
        }
        Pl[qrow * 40 + l15]      = f2b(exp2f(u0));
        Pl[qrow * 40 + 16 + l15] = f2b(exp2f(u1));
      }
    // PV (+ ones row for l): A = P from LDS, B = V^T rows (18 MFMA)
    v8s pf[2];
    pf[0] = *(const v8s*)&Pl[l15 * 40 + quad * 8];
    pf[1] = *(const v8s*)&Pl[(16 + l15) * 40 + quad * 8];
    #pragma unroll
    for (int di = 0; di < 9; ++di) {
      const v8s vt = *(const v8s*)(Vb + (size_t)(di * 16 + l15) * T_ + j0 + quad * 8);
      o[0][di] = __builtin_amdgcn_mfma_f32_16x16x32_bf16(asbf(pf[0]), asbf(vt), o[0][di], 0, 0, 0);
      o[1][di] = __builtin_amdgcn_mfma_f32_16x16x32_bf16(asbf(pf[1]), asbf(vt), o[1][di], 0, 0, 0);
    }
  }

  // merge the two key-halves: half1 publishes partials, half0 combines
  if (half == 1) {
    #pragma unroll
    for (int mi = 0; mi < 2; ++mi)
      #pragma unroll
      for (int di = 0; di < 9; ++di)
        Olds[pairsel][mi * 9 + di][lane] = o[mi][di];
  }
  __syncthreads();
  if (half == 1) return;
  #pragma unroll
  for (int mi = 0; mi < 2; ++mi)
    #pragma unroll
    for (int di = 0; di < 9; ++di)
      o[mi][di] += Olds[pairsel][mi * 9 + di][lane];

  // epilogue: l broadcast (col 0 of the ones-column lives in lanes l15==0)
  #pragma unroll
  for (int mi = 0; mi < 2; ++mi) {
    float inv[4];
    #pragma unroll
    for (int r = 0; r < 4; ++r) {
      const float lb = __shfl(o[mi][8][r], lane & 48, 64);
      inv[r] = 1.f / lb;
    }
    #pragma unroll
    for (int di = 0; di < 8; ++di)
      #pragma unroll
      for (int r = 0; r < 4; ++r) {
        const int t   = q0 + mi * 16 + quad * 4 + r;
        const int col = h * 128 + di * 16 + l15;
        ctx[(size_t)(b * T_ + t) * (NH_ * HD_) + col] = f2b(o[mi][di][r] * inv[r]);
      }
  }
}

// ---------------------------------------------------------------------------
extern "C" void kernel_launch(void* const* d_in, const int* in_sizes, int n_in,
                              void* d_out, int out_size, void* d_ws, size_t ws_size,
                              hipStream_t stream) {
  (void)in_sizes; (void)n_in; (void)out_size; (void)ws_size;
  const float* x  = (const float*)d_in[0];
  // d_in[1] = attn_mask (causal; applied analytically)
  const float* Wq = (const float*)d_in[2];
  const float* Wk = (const float*)d_in[3];
  const float* Wv = (const float*)d_in[4];
  const float* Wo = (const float*)d_in[5];
  const float* Wo_ = Wo;
  const float* qw = (const float*)d_in[6];
  const float* kw = (const float*)d_in[7];
  float* out = (float*)d_out;

  // workspace (lifetime-aliased, 68.2 MB):
  //   [0,        8.39M)  WoT              live: whole
  //   [8.39M,   25.17M)  WqkvT            live: until QKV gemm
  //   [8.39M,   16.78M)  Vh               live: norm_rope -> V-transpose (aliases dead WqkvT)
  //   [16.78M,  26.21M)  VhTp [16][144][T] live: fill/transpose -> attn (dead WqkvT + dead x_bf tail)
  //   [25.17M,  41.94M)  x_bf             live: cvt -> QKV gemm
  //   [26.21M,  42.99M)  ctx              live: attn -> out gemm (aliases dead x_bf)
  //   [42.99M,  59.77M)  Qh
  //   [59.77M,  68.16M)  Kh
  char* ws = (char*)d_ws;
  u16* WoT   = (u16*)(ws);
  u16* WqkvT = (u16*)(ws + 8388608);
  u16* Vh    = (u16*)(ws + 8388608);
  u16* VhTp  = (u16*)(ws + 16777216);
  u16* x_bf  = (u16*)(ws + 25165824);
  u16* ctx   = (u16*)(ws + 26214400);
  u16* Qh    = (u16*)(ws + 42991616);
  u16* Kh    = (u16*)(ws + 59768832);
  // QKV bf16 [4096][4096] scratch lives in d_out (f32 8.4M elems), dead
  // before the final f32 GEMM overwrites d_out.
  u16* QKV = (u16*)d_out;

  cvt_f32_bf16<<<2048, 256, 0, stream>>>(x, x_bf, 2097152u);
  transpose_f32_bf16<<<dim3(32, 32), 256, 0, stream>>>(Wq, WqkvT,               2048, 2048);
  transpose_f32_bf16<<<dim3(16, 32), 256, 0, stream>>>(Wk, WqkvT + 2048 * 2048, 2048, 1024);
  transpose_f32_bf16<<<dim3(16, 32), 256, 0, stream>>>(Wv, WqkvT + 3072 * 2048, 2048, 1024);
  transpose_f32_bf16<<<dim3(32, 32), 256, 0, stream>>>(Wo_, WoT,                2048, 2048);

  // QKV projection (bf16 out into d_out scratch); WqkvT/x_bf dead after
  gemm_bt<false><<<dim3(32, 32), 256, 0, stream>>>(x_bf, WqkvT, QKV, 4096, 4096, 2048);

  norm_rope_scatter<<<dim3(32768), 256, 0, stream>>>(QKV, qw, kw, Qh, Kh, Vh);
  fill_vones<<<256, 256, 0, stream>>>(VhTp);
  transpose_bf16<<<dim3(2, 32, 16), 256, 0, stream>>>(Vh, VhTp, 2048, 128,
                                                      (long)2048 * 128, (long)144 * 2048);

  attn_fused2<<<dim3(1024), 256, 0, stream>>>(Qh, Kh, VhTp, ctx);

  // output projection: f32 store into d_out (overwrites QKV scratch fully)
  gemm_bt<true><<<dim3(16, 32), 256, 0, stream>>>(ctx, WoT, (void*)out, 4096, 2048, 2048);
}